// Round 1
// baseline (2055.464 us; speedup 1.0000x reference)
//
#include <hip/hip_runtime.h>
#include <hip/hip_fp16.h>
#include <stdint.h>

#define Bsz 64
#define Tsz 1024
#define Dsz 256
#define UNITSn 256
#define Zdim 1024      // 4*UNITS
#define K2n 128        // 256/2 packed k-pairs
#define WREG 24        // uint4 (4 k-pairs) per j-column kept in VGPRs  (k2 0..95)
#define WLDS 8         // uint4 per j-column kept in LDS                (k2 96..127)

typedef _Float16 half2v __attribute__((ext_vector_type(2)));

__device__ __forceinline__ float dot2acc(uint32_t w, uint32_t h, float acc) {
#if __has_builtin(__builtin_amdgcn_fdot2)
  return __builtin_amdgcn_fdot2(__builtin_bit_cast(half2v, w),
                                __builtin_bit_cast(half2v, h), acc, false);
#else
  __half2 wv = __builtin_bit_cast(__half2, w);
  __half2 hv = __builtin_bit_cast(__half2, h);
  acc = fmaf(__half2float(__low2half(wv)),  __half2float(__low2half(hv)),  acc);
  acc = fmaf(__half2float(__high2half(wv)), __half2float(__high2half(hv)), acc);
  return acc;
#endif
}

__device__ __forceinline__ void dot8(const uint4& w0, const uint4& w1, const uint4& h4,
                                     float& a0, float& a1) {
  a0 = dot2acc(w0.x, h4.x, a0); a0 = dot2acc(w0.y, h4.y, a0);
  a0 = dot2acc(w0.z, h4.z, a0); a0 = dot2acc(w0.w, h4.w, a0);
  a1 = dot2acc(w1.x, h4.x, a1); a1 = dot2acc(w1.y, h4.y, a1);
  a1 = dot2acc(w1.z, h4.z, a1); a1 = dot2acc(w1.w, h4.w, a1);
}

__device__ __forceinline__ float sigm(float x)   { return 1.0f / (1.0f + __expf(-x)); }
__device__ __forceinline__ float tanh_f(float x) { return 1.0f - 2.0f / (__expf(2.0f * x) + 1.0f); }

// Pack W[256][1024] fp32 -> Wp2[j][k2] = half2(W[2k2][j], W[2k2+1][j])
__global__ void convert_w(const float* __restrict__ W, uint32_t* __restrict__ Wp2) {
  int idx = blockIdx.x * 256 + threadIdx.x;     // idx = j*128 + k2
  if (idx >= Zdim * K2n) return;
  int j = idx >> 7, k2 = idx & 127;
  float w0 = W[(size_t)(2 * k2) * Zdim + j];
  float w1 = W[(size_t)(2 * k2 + 1) * Zdim + j];
  __half2 p = __floats2half2_rn(w0, w1);
  Wp2[idx] = __builtin_bit_cast(uint32_t, p);
}

// xz[(tloc*64 + b)*1024 + n] = x[b][t0+tloc][:] @ U[:,n] + bias[n]   (fp32 GEMM)
// grid (16, Tc): bx = n-tile (fast dim -> 16 consecutive WGs share A rows in L2), by = tloc
__global__ __launch_bounds__(256) void proj_gemm(
    const float* __restrict__ x, const float* __restrict__ U,
    const float* __restrict__ bias, float* __restrict__ xz, int t0) {
  __shared__ float At[32][68];   // [k][m] transposed A tile, padded
  __shared__ float Bt[32][68];   // [k][n] tile, padded
  const int tid  = threadIdx.x;
  const int n0   = blockIdx.x * 64;
  const int tloc = blockIdx.y;
  const int t    = t0 + tloc;
  const int tm = tid >> 4, tn = tid & 15;          // compute map: m=4tm+i, n=4tn+j
  const int am = tid >> 3, ak = (tid & 7) * 4;     // A staging: row am(=b), k offset
  const int bk = tid >> 4, bn = (tid & 15) * 4;    // B staging
  const float* xb = x + (size_t)t * Dsz;           // + b*(Tsz*Dsz) + k

  float acc[4][4] = {};
  for (int k0 = 0; k0 < Dsz; k0 += 32) {
    float4 a0 = *(const float4*)(xb + (size_t)am * (Tsz * Dsz) + k0 + ak);
    float4 a1 = *(const float4*)(xb + (size_t)(am + 32) * (Tsz * Dsz) + k0 + ak);
    float4 b0 = *(const float4*)(U + (size_t)(k0 + bk) * Zdim + n0 + bn);
    float4 b1 = *(const float4*)(U + (size_t)(k0 + bk + 16) * Zdim + n0 + bn);
    __syncthreads();
    At[ak + 0][am] = a0.x; At[ak + 1][am] = a0.y; At[ak + 2][am] = a0.z; At[ak + 3][am] = a0.w;
    At[ak + 0][am + 32] = a1.x; At[ak + 1][am + 32] = a1.y; At[ak + 2][am + 32] = a1.z; At[ak + 3][am + 32] = a1.w;
    *(float4*)&Bt[bk][bn]      = b0;
    *(float4*)&Bt[bk + 16][bn] = b1;
    __syncthreads();
#pragma unroll
    for (int kk = 0; kk < 32; kk++) {
      float4 av = *(const float4*)&At[kk][tm * 4];
      float4 bv = *(const float4*)&Bt[kk][tn * 4];
      float a_[4] = {av.x, av.y, av.z, av.w};
      float b_[4] = {bv.x, bv.y, bv.z, bv.w};
#pragma unroll
      for (int i = 0; i < 4; i++)
#pragma unroll
        for (int j = 0; j < 4; j++) acc[i][j] = fmaf(a_[i], b_[j], acc[i][j]);
    }
  }
  float4 bb = *(const float4*)&bias[n0 + tn * 4];
  float bias_[4] = {bb.x, bb.y, bb.z, bb.w};
#pragma unroll
  for (int i = 0; i < 4; i++) {
    float4 o;
    o.x = acc[i][0] + bias_[0]; o.y = acc[i][1] + bias_[1];
    o.z = acc[i][2] + bias_[2]; o.w = acc[i][3] + bias_[3];
    *(float4*)(xz + ((size_t)tloc * 64 + tm * 4 + i) * Zdim + n0 + tn * 4) = o;
  }
}

// One WG per batch. 512 threads; thread tid owns z-columns {tid, tid+512}.
// W (f16 pairs): k2 0..95 in VGPRs (192 dwords/thread), k2 96..127 in LDS (128KB).
// h kept as packed f16 pairs in LDS (double-buffered); c fp32 in VGPR of thread u<256.
__global__ __launch_bounds__(512, 2) void lstm_chunk(
    const float* __restrict__ xz, const uint32_t* __restrict__ Wp2,
    float* __restrict__ out, uint4* __restrict__ h_state, float* __restrict__ c_state,
    int t0, int Tc, int n_out) {
  extern __shared__ uint32_t smem[];
  uint32_t* Wl = smem;                        // 2*WLDS*512 uint4 = 32768 dwords (128KB)
  uint4* hq    = (uint4*)(smem + 32768);      // [2][32] uint4 = 2 x 256 f16
  float* zf    = (float*)(smem + 32768 + 256);
  float* zo    = zf + 256;

  const int tid = threadIdx.x;
  const int b   = blockIdx.x;

  const uint4* wp0 = (const uint4*)(Wp2 + (size_t)tid * K2n);
  const uint4* wp1 = (const uint4*)(Wp2 + (size_t)(tid + 512) * K2n);
  uint4 w4[2][WREG];
#pragma unroll
  for (int i = 0; i < WREG; i++) { w4[0][i] = wp0[i]; w4[1][i] = wp1[i]; }
#pragma unroll
  for (int q2 = 0; q2 < WLDS; q2++) {
    *(uint4*)(Wl + (size_t)(q2 * 512 + tid) * 4)          = wp0[WREG + q2];
    *(uint4*)(Wl + (size_t)((WLDS + q2) * 512 + tid) * 4) = wp1[WREG + q2];
  }

  float c = 0.0f;
  if (t0 == 0) {
    if (tid < 64) hq[tid] = make_uint4(0, 0, 0, 0);
  } else {
    if (tid < 32)  hq[tid] = h_state[(size_t)b * 32 + tid];
    if (tid < 256) c = c_state[(size_t)b * 256 + tid];
  }
  __syncthreads();

  const float* xzb = xz + (size_t)b * Zdim;
  float nx0 = xzb[tid];
  float nx1 = xzb[tid + 512];
  for (int tl = 0; tl < Tc; tl++) {
    const int buf = tl & 1;
    float acc0 = nx0, acc1 = nx1;
    if (tl + 1 < Tc) {  // prefetch next step's xz
      nx0 = xzb[(size_t)(tl + 1) * (Bsz * Zdim) + tid];
      nx1 = xzb[(size_t)(tl + 1) * (Bsz * Zdim) + tid + 512];
    }
    const uint4* hc = hq + buf * 32;
#pragma unroll
    for (int q = 0; q < WREG; q++) {
      uint4 h4 = hc[q];
      dot8(w4[0][q], w4[1][q], h4, acc0, acc1);
    }
#pragma unroll
    for (int q2 = 0; q2 < WLDS; q2++) {
      uint4 h4 = hc[WREG + q2];
      uint4 wa = *(const uint4*)(Wl + (size_t)(q2 * 512 + tid) * 4);
      uint4 wb = *(const uint4*)(Wl + (size_t)((WLDS + q2) * 512 + tid) * 4);
      dot8(wa, wb, h4, acc0, acc1);
    }
    if (tid >= 256) { zf[tid - 256] = acc0; zo[tid - 256] = acc1; }
    __syncthreads();
    if (tid < 256) {
      float ig = sigm(acc0);        // z0
      float gg = tanh_f(acc1);      // z2
      float fg = sigm(zf[tid]);     // z1
      float og = sigm(zo[tid]);     // z3
      c = fg * c + ig * gg;
      float hn = og * tanh_f(c);
      int ot = (t0 + tl) - (Tsz - n_out);
      if (ot >= 0) out[((size_t)b * n_out + ot) * UNITSn + tid] = hn;
      ((__half*)(hq + (buf ^ 1) * 32))[tid] = __float2half(hn);
    }
    __syncthreads();
  }
  if (tid < 32)  h_state[(size_t)b * 32 + tid] = hq[(Tc & 1) * 32 + tid];
  if (tid < 256) c_state[(size_t)b * 256 + tid] = c;
}

extern "C" void kernel_launch(void* const* d_in, const int* in_sizes, int n_in,
                              void* d_out, int out_size, void* d_ws, size_t ws_size,
                              hipStream_t stream) {
  const float* x    = (const float*)d_in[0];
  const float* U    = (const float*)d_in[1];
  const float* W    = (const float*)d_in[2];
  const float* bias = (const float*)d_in[3];
  float* out = (float*)d_out;
  const int n_out = out_size / (Bsz * UNITSn);   // 32

  uint8_t* ws = (uint8_t*)d_ws;
  uint32_t* Wp2  = (uint32_t*)ws;                  // 512 KB packed f16 W
  uint4* h_state = (uint4*)(ws + (512u << 10));    // 32 KB
  float* c_state = (float*)(ws + (544u << 10));    // 64 KB
  float* xz      = (float*)(ws + (1u << 20));      // Tc*64*1024 fp32

  int Tc = Tsz;
  while (Tc > 1 && (size_t)(1u << 20) + (size_t)Tc * (Bsz * Zdim) * 4 > ws_size) Tc >>= 1;

  convert_w<<<dim3((Zdim * K2n + 255) / 256), dim3(256), 0, stream>>>(W, Wp2);

  const int ldsBytes = (32768 + 256 + 512) * 4;    // 134144 B
  hipFuncSetAttribute((const void*)lstm_chunk,
                      hipFuncAttributeMaxDynamicSharedMemorySize, ldsBytes);

  for (int t0 = 0; t0 < Tsz; t0 += Tc) {
    proj_gemm<<<dim3(16, Tc), dim3(256), 0, stream>>>(x, U, bias, xz, t0);
    lstm_chunk<<<dim3(Bsz), dim3(512), ldsBytes, stream>>>(xz, Wp2, out, h_state,
                                                           c_state, t0, Tc, n_out);
  }
}